// Round 2
// baseline (590.405 us; speedup 1.0000x reference)
//
#include <hip/hip_runtime.h>
#include <stdint.h>

// ---------- types ----------
typedef __attribute__((ext_vector_type(4))) float  f32x4;
typedef __attribute__((ext_vector_type(8))) short  short8;   // 8 bf16 in 4 VGPRs
typedef __attribute__((ext_vector_type(4))) short  short4v;  // 4 bf16, 8B

#define MFMA16(a,b,c) __builtin_amdgcn_mfma_f32_16x16x32_bf16((a),(b),(c),0,0,0)

static __device__ __forceinline__ unsigned short f2bf(float f) {
    unsigned int u = __float_as_uint(f);
    u += 0x7FFFu + ((u >> 16) & 1u);   // round-to-nearest-even
    return (unsigned short)(u >> 16);
}
static __device__ __forceinline__ float bflo(unsigned int v) {   // low bf16 -> f32
    return __uint_as_float(v << 16);
}
static __device__ __forceinline__ float bfhi(unsigned int v) {   // high bf16 -> f32
    return __uint_as_float(v & 0xFFFF0000u);
}
static __device__ __forceinline__ unsigned int packbf(float a, float b) {
    return (unsigned int)f2bf(a) | ((unsigned int)f2bf(b) << 16);
}

// B=2, S=2048, C=512, E=512, H=8, HD=64
// reshape(B,H,S,HD) without transpose => per (b,h): contiguous [2048][64] slab
// at flat offset b*1048576 + h*131072 in the [4096][512] projection output.

// =====================================================================
// Kernel 1: fused QKV projection. Y[m,e] = sum_c x[m,c]*W[e,c] + b[e]
// All three outputs written linearly as bf16 [4096][512].
// =====================================================================
__global__ __launch_bounds__(256) void qkv_gemm(
    const float* __restrict__ x,
    const float* __restrict__ Wq, const float* __restrict__ bq,
    const float* __restrict__ Wk, const float* __restrict__ bk,
    const float* __restrict__ Wv, const float* __restrict__ bv,
    unsigned short* __restrict__ Qb, unsigned short* __restrict__ Kb,
    unsigned short* __restrict__ Vb)
{
    __shared__ unsigned short As[128 * 40];  // stride 40 bf16 = 80B
    __shared__ unsigned short Bs[128 * 40];

    const int tid  = threadIdx.x;
    const int lane = tid & 63;
    const int wid  = tid >> 6;
    const int g = lane >> 4, c = lane & 15;
    const int wr = wid >> 1, wc = wid & 1;
    const int bm    = blockIdx.x;        // 0..31
    const int widx  = blockIdx.y >> 2;   // 0..2  (Q/K/V)
    const int ntile = blockIdx.y & 3;    // 0..3

    const float* W    = (widx == 0) ? Wq : (widx == 1) ? Wk : Wv;
    const float* bias = (widx == 0) ? bq : (widx == 1) ? bk : bv;
    unsigned short* Y = (widx == 0) ? Qb : (widx == 1) ? Kb : Vb;
    const float* Abase = x + (size_t)bm * 128 * 512;
    const float* Bbase = W + (size_t)ntile * 128 * 512;

    f32x4 acc[4][4];
    #pragma unroll
    for (int m = 0; m < 4; m++)
        #pragma unroll
        for (int n = 0; n < 4; n++) acc[m][n] = (f32x4){0.f, 0.f, 0.f, 0.f};

    for (int kk = 0; kk < 512; kk += 32) {
        #pragma unroll
        for (int i = 0; i < 4; i++) {
            int f  = i * 256 + tid;
            int rr = f >> 3;
            int cc = (f & 7) * 4;
            f32x4 va = *(const f32x4*)(Abase + rr * 512 + kk + cc);
            f32x4 vb = *(const f32x4*)(Bbase + rr * 512 + kk + cc);
            short4v sa, sb;
            #pragma unroll
            for (int q = 0; q < 4; q++) { sa[q] = (short)f2bf(va[q]); sb[q] = (short)f2bf(vb[q]); }
            *(short4v*)(&As[rr * 40 + cc]) = sa;
            *(short4v*)(&Bs[rr * 40 + cc]) = sb;
        }
        __syncthreads();

        short8 af[4], bfr[4];
        #pragma unroll
        for (int m = 0; m < 4; m++) af[m]  = *(const short8*)(&As[(wr * 64 + m * 16 + c) * 40 + g * 8]);
        #pragma unroll
        for (int n = 0; n < 4; n++) bfr[n] = *(const short8*)(&Bs[(wc * 64 + n * 16 + c) * 40 + g * 8]);
        #pragma unroll
        for (int m = 0; m < 4; m++)
            #pragma unroll
            for (int n = 0; n < 4; n++)
                acc[m][n] = MFMA16(af[m], bfr[n], acc[m][n]);
        __syncthreads();
    }

    #pragma unroll
    for (int n = 0; n < 4; n++) {
        int colW = ntile * 128 + wc * 64 + n * 16 + c;
        float bb = bias[colW];
        #pragma unroll
        for (int m = 0; m < 4; m++) {
            #pragma unroll
            for (int r = 0; r < 4; r++) {
                int row = bm * 128 + wr * 64 + m * 16 + g * 4 + r;   // 0..4095
                Y[(size_t)row * 512 + colW] = f2bf(acc[m][n][r] + bb);
            }
        }
    }
}

// =====================================================================
// Kernel 1.5: V transpose.  Vb [4096][512] bf16 -> Vt[bh=16][d=64][s2=2048].
// head-view element (bh, s2, d) lives at Vb row b*2048 + h*256 + (s2>>3),
// col (s2&7)*64 + d.
// grid (32 s2-tiles, 16 bh), block 256.
// =====================================================================
__global__ __launch_bounds__(256) void v_transpose(
    const unsigned short* __restrict__ Vb, unsigned short* __restrict__ Vt)
{
    __shared__ unsigned short T[8][520];   // 8 source rows x 512 cols (+pad)

    const int tid = threadIdx.x;
    const int t   = blockIdx.x;            // s2 tile: s2 = t*64 + sj
    const int bh  = blockIdx.y;
    const int b = bh >> 3, h = bh & 7;

    #pragma unroll
    for (int i = 0; i < 2; i++) {
        int idx = i * 256 + tid;           // short8 id, 512 total
        int j   = idx >> 6;                // source row 0..7
        int cc  = (idx & 63) * 8;
        short8 v = *(const short8*)(Vb + (size_t)(b * 2048 + h * 256 + t * 8 + j) * 512 + cc);
        *(short8*)(&T[j][cc]) = v;
    }
    __syncthreads();

    const int d   = tid >> 2;              // 0..63
    const int sjb = (tid & 3) * 16;        // 0,16,32,48
    unsigned short tmp[16];
    #pragma unroll
    for (int i = 0; i < 16; i++) {
        int sj = sjb + i;
        tmp[i] = T[sj >> 3][(sj & 7) * 64 + d];
    }
    unsigned short* dst = Vt + ((size_t)(bh * 64 + d) * 2048) + t * 64 + sjb;
    *(short8*)(dst)     = *(short8*)(&tmp[0]);
    *(short8*)(dst + 8) = *(short8*)(&tmp[8]);
}

// =====================================================================
// Kernel 2: fused attention, single pass over K with register-resident logits.
// grid (128 qgroups, 16 bh), block 256 (4 waves).
// Block owns 16 q rows; wave w owns keys [w*512, (w+1)*512).
// Phase 1: QK^T (MFMA), mask+scale, store bf16 logits in regs, track row max.
// Cross-wave max via LDS. Phase 2: e=exp(l-m) (overwrite regs), cross-wave denom.
// Phase 3: p=e/d, blend with dist, store attn, LDS round-trip -> PV MFMA.
// Phase 4: cross-wave PV reduce via LDS, store ctx bf16 in (B,S,E) layout.
// =====================================================================
__global__ __launch_bounds__(256) void attn_kernel(
    const unsigned short* __restrict__ Qb, const unsigned short* __restrict__ Kb,
    const unsigned short* __restrict__ Vt,
    const float* __restrict__ dist, const int* __restrict__ mask,
    float* __restrict__ attn_out, unsigned short* __restrict__ ctx_bf)
{
    __shared__ unsigned short AP[4][16][72];   // per-wave P tile (bf16)
    __shared__ float red[4][2][16];            // [wave][max|sum][row]
    __shared__ float Cred[4][16][64];          // PV partials

    const int tid = threadIdx.x;
    const int lane = tid & 63, wid = tid >> 6;
    const int g = lane >> 4, c = lane & 15;
    const int qg = blockIdx.x;       // 0..127
    const int bh = blockIdx.y;       // 0..15
    const int b = bh >> 3, h = bh & 7;

    const unsigned short* Qh  = Qb + (size_t)b * 1048576 + (size_t)h * 131072;
    const unsigned short* Kh  = Kb + (size_t)b * 1048576 + (size_t)h * 131072;
    const unsigned short* Vth = Vt + (size_t)bh * 131072;       // [64 d][2048 s2]
    const float* distb = dist + (size_t)bh * 4194304;
    float*       outb  = attn_out + (size_t)bh * 4194304;
    const int*   maskb = mask + b * 2048;

    const int qrow    = qg * 16;          // head-local base row
    const int keybase = wid * 512;        // this wave's key range

    short8 qf[2];
    #pragma unroll
    for (int ks = 0; ks < 2; ks++)
        qf[ks] = *(const short8*)(Qh + (size_t)(qrow + c) * 64 + ks * 32 + g * 8);

    // ---------------- phase 1: logits + per-wave max ----------------
    unsigned int pl[8][4][2];             // packed bf16 logits [kb8][n][(r0,r1)|(r2,r3)]
    float lmax[4] = {-3e38f, -3e38f, -3e38f, -3e38f};

    #pragma unroll
    for (int kb8 = 0; kb8 < 8; kb8++) {
        const int kb = keybase + kb8 * 64;
        short8 kf[4][2];
        #pragma unroll
        for (int n = 0; n < 4; n++)
            #pragma unroll
            for (int ks = 0; ks < 2; ks++)
                kf[n][ks] = *(const short8*)(Kh + (size_t)(kb + n * 16 + c) * 64 + ks * 32 + g * 8);
        #pragma unroll
        for (int n = 0; n < 4; n++) {
            f32x4 z = (f32x4){0.f, 0.f, 0.f, 0.f};
            z = MFMA16(qf[0], kf[n][0], z);
            z = MFMA16(qf[1], kf[n][1], z);
            const int mv = maskb[kb + n * 16 + c];
            float l[4];
            #pragma unroll
            for (int r = 0; r < 4; r++) {
                l[r] = mv ? -1250.f : z[r] * 0.125f;
                lmax[r] = fmaxf(lmax[r], l[r]);
            }
            pl[kb8][n][0] = packbf(l[0], l[1]);
            pl[kb8][n][1] = packbf(l[2], l[3]);
        }
    }
    #pragma unroll
    for (int r = 0; r < 4; r++) {
        #pragma unroll
        for (int off = 1; off < 16; off <<= 1)
            lmax[r] = fmaxf(lmax[r], __shfl_xor(lmax[r], off));
    }
    if (c == 0) {
        #pragma unroll
        for (int r = 0; r < 4; r++) red[wid][0][g * 4 + r] = lmax[r];
    }
    __syncthreads();
    float m[4];
    #pragma unroll
    for (int r = 0; r < 4; r++) {
        int row = g * 4 + r;
        m[r] = fmaxf(fmaxf(red[0][0][row], red[1][0][row]),
                     fmaxf(red[2][0][row], red[3][0][row]));
    }

    // ---------------- phase 2: exp + denom ----------------
    float dsum[4] = {0.f, 0.f, 0.f, 0.f};
    #pragma unroll
    for (int kb8 = 0; kb8 < 8; kb8++) {
        #pragma unroll
        for (int n = 0; n < 4; n++) {
            #pragma unroll
            for (int pi = 0; pi < 2; pi++) {
                unsigned int v = pl[kb8][n][pi];
                float e0 = __expf(bflo(v) - m[pi * 2]);
                float e1 = __expf(bfhi(v) - m[pi * 2 + 1]);
                dsum[pi * 2]     += e0;
                dsum[pi * 2 + 1] += e1;
                pl[kb8][n][pi] = packbf(e0, e1);
            }
        }
    }
    #pragma unroll
    for (int r = 0; r < 4; r++) {
        #pragma unroll
        for (int off = 1; off < 16; off <<= 1)
            dsum[r] += __shfl_xor(dsum[r], off);
    }
    if (c == 0) {
        #pragma unroll
        for (int r = 0; r < 4; r++) red[wid][1][g * 4 + r] = dsum[r];
    }
    __syncthreads();
    float invd[4];
    #pragma unroll
    for (int r = 0; r < 4; r++) {
        int row = g * 4 + r;
        invd[r] = 1.f / (red[0][1][row] + red[1][1][row] + red[2][1][row] + red[3][1][row]);
    }

    // ---------------- phase 3: emit probs + PV ----------------
    f32x4 cacc[4];
    #pragma unroll
    for (int nd = 0; nd < 4; nd++) cacc[nd] = (f32x4){0.f, 0.f, 0.f, 0.f};

    #pragma unroll
    for (int kb8 = 0; kb8 < 8; kb8++) {
        const int kb = keybase + kb8 * 64;
        #pragma unroll
        for (int n = 0; n < 4; n++) {
            const int key = kb + n * 16 + c;
            #pragma unroll
            for (int pi = 0; pi < 2; pi++) {
                unsigned int v = pl[kb8][n][pi];
                #pragma unroll
                for (int rr = 0; rr < 2; rr++) {
                    const int r = pi * 2 + rr;
                    float e = rr ? bfhi(v) : bflo(v);
                    float p = e * invd[r];
                    size_t off = (size_t)(qrow + g * 4 + r) * 2048 + key;
                    float ap = 0.5f * (p + distb[off]);
                    outb[off] = ap;
                    AP[wid][g * 4 + r][n * 16 + c] = f2bf(ap);
                }
            }
        }
        short8 apf[2];
        #pragma unroll
        for (int ks = 0; ks < 2; ks++)
            apf[ks] = *(const short8*)(&AP[wid][c][ks * 32 + g * 8]);
        #pragma unroll
        for (int nd = 0; nd < 4; nd++) {
            #pragma unroll
            for (int ks = 0; ks < 2; ks++) {
                short8 vf = *(const short8*)(Vth + (size_t)(nd * 16 + c) * 2048 + kb + ks * 32 + g * 8);
                cacc[nd] = MFMA16(apf[ks], vf, cacc[nd]);
            }
        }
    }

    // ---------------- phase 4: cross-wave PV reduce + ctx store ----------------
    #pragma unroll
    for (int nd = 0; nd < 4; nd++)
        #pragma unroll
        for (int r = 0; r < 4; r++)
            Cred[wid][g * 4 + r][nd * 16 + c] = cacc[nd][r];
    __syncthreads();

    for (int e = tid; e < 1024; e += 256) {
        int row = e >> 6, d = e & 63;
        float s = Cred[0][row][d] + Cred[1][row][d] + Cred[2][row][d] + Cred[3][row][d];
        int i = qrow + row;
        ctx_bf[(size_t)(b * 2048 + i) * 512 + h * 64 + d] = f2bf(s);
    }
}

// =====================================================================
// Kernel 3: out = ctx @ Wo^T + bo.  A bf16 [4096][512], B fp32 [512][512] (NT).
// =====================================================================
__global__ __launch_bounds__(256) void out_gemm(
    const unsigned short* __restrict__ A,
    const float* __restrict__ Wo, const float* __restrict__ bo,
    float* __restrict__ out)
{
    __shared__ unsigned short As[128 * 40];
    __shared__ unsigned short Bs[128 * 40];

    const int tid  = threadIdx.x;
    const int lane = tid & 63;
    const int wid  = tid >> 6;
    const int g = lane >> 4, c = lane & 15;
    const int wr = wid >> 1, wc = wid & 1;
    const int bm    = blockIdx.x;   // 0..31
    const int ntile = blockIdx.y;   // 0..3

    const unsigned short* Abase = A + (size_t)bm * 128 * 512;
    const float* Bbase = Wo + (size_t)ntile * 128 * 512;

    f32x4 acc[4][4];
    #pragma unroll
    for (int m = 0; m < 4; m++)
        #pragma unroll
        for (int n = 0; n < 4; n++) acc[m][n] = (f32x4){0.f, 0.f, 0.f, 0.f};

    for (int kk = 0; kk < 512; kk += 32) {
        #pragma unroll
        for (int i = 0; i < 2; i++) {
            int f8 = i * 256 + tid;
            int rr = f8 >> 2;
            int cc = (f8 & 3) * 8;
            short8 va = *(const short8*)(Abase + (size_t)rr * 512 + kk + cc);
            *(short8*)(&As[rr * 40 + cc]) = va;
        }
        #pragma unroll
        for (int i = 0; i < 4; i++) {
            int f  = i * 256 + tid;
            int rr = f >> 3;
            int cc = (f & 7) * 4;
            f32x4 vb = *(const f32x4*)(Bbase + (size_t)rr * 512 + kk + cc);
            short4v sb;
            #pragma unroll
            for (int q = 0; q < 4; q++) sb[q] = (short)f2bf(vb[q]);
            *(short4v*)(&Bs[rr * 40 + cc]) = sb;
        }
        __syncthreads();

        short8 af[4], bfr[4];
        #pragma unroll
        for (int m = 0; m < 4; m++) af[m]  = *(const short8*)(&As[(wr * 64 + m * 16 + c) * 40 + g * 8]);
        #pragma unroll
        for (int n = 0; n < 4; n++) bfr[n] = *(const short8*)(&Bs[(wc * 64 + n * 16 + c) * 40 + g * 8]);
        #pragma unroll
        for (int m = 0; m < 4; m++)
            #pragma unroll
            for (int n = 0; n < 4; n++)
                acc[m][n] = MFMA16(af[m], bfr[n], acc[m][n]);
        __syncthreads();
    }

    #pragma unroll
    for (int n = 0; n < 4; n++) {
        int col = ntile * 128 + wc * 64 + n * 16 + c;
        float bb = bo[col];
        #pragma unroll
        for (int m = 0; m < 4; m++) {
            #pragma unroll
            for (int r = 0; r < 4; r++) {
                int row = bm * 128 + wr * 64 + m * 16 + g * 4 + r;
                out[(size_t)row * 512 + col] = acc[m][n][r] + bb;
            }
        }
    }
}

// =====================================================================
extern "C" void kernel_launch(void* const* d_in, const int* in_sizes, int n_in,
                              void* d_out, int out_size, void* d_ws, size_t ws_size,
                              hipStream_t stream)
{
    const float* x    = (const float*)d_in[0];
    const float* dist = (const float*)d_in[1];
    const int*   mask = (const int*)d_in[2];
    const float* Wq   = (const float*)d_in[3];
    const float* bq   = (const float*)d_in[4];
    const float* Wk   = (const float*)d_in[5];
    const float* bk   = (const float*)d_in[6];
    const float* Wv   = (const float*)d_in[7];
    const float* bv   = (const float*)d_in[8];
    const float* Wo   = (const float*)d_in[9];
    const float* bo   = (const float*)d_in[10];

    float* out      = (float*)d_out;            // (2,2048,512)   = 2,097,152
    float* attn_out = out + 2097152;            // (2,8,2048,2048)= 67,108,864

    char* ws = (char*)d_ws;
    unsigned short* Qb  = (unsigned short*)(ws);                 // 4 MB
    unsigned short* Kb  = (unsigned short*)(ws + (4u << 20));    // 4 MB
    unsigned short* Vb  = (unsigned short*)(ws + (8u << 20));    // 4 MB (linear V)
    unsigned short* Vt  = (unsigned short*)(ws + (12u << 20));   // 4 MB [16][64][2048]
    unsigned short* ctx = (unsigned short*)(ws + (8u << 20));    // reuses Vb (consumed)

    qkv_gemm   <<<dim3(32, 12), 256, 0, stream>>>(x, Wq, bq, Wk, bk, Wv, bv, Qb, Kb, Vb);
    v_transpose<<<dim3(32, 16), 256, 0, stream>>>(Vb, Vt);
    attn_kernel<<<dim3(128, 16), 256, 0, stream>>>(Qb, Kb, Vt, dist, mask, attn_out, ctx);
    out_gemm   <<<dim3(32, 4),  256, 0, stream>>>(ctx, Wo, bo, out);
}

// Round 3
// 245.628 us; speedup vs baseline: 2.4037x; 2.4037x over previous
//
#include <hip/hip_runtime.h>
#include <stdint.h>

// ---------- types ----------
typedef __attribute__((ext_vector_type(4))) float  f32x4;
typedef __attribute__((ext_vector_type(8))) short  short8;   // 8 bf16 in 4 VGPRs
typedef __attribute__((ext_vector_type(4))) short  short4v;  // 4 bf16, 8B

#define MFMA16(a,b,c) __builtin_amdgcn_mfma_f32_16x16x32_bf16((a),(b),(c),0,0,0)

static __device__ __forceinline__ unsigned short f2bf(float f) {
    unsigned int u = __float_as_uint(f);
    u += 0x7FFFu + ((u >> 16) & 1u);   // round-to-nearest-even
    return (unsigned short)(u >> 16);
}
static __device__ __forceinline__ float bflo(unsigned int v) {   // low bf16 -> f32
    return __uint_as_float(v << 16);
}
static __device__ __forceinline__ float bfhi(unsigned int v) {   // high bf16 -> f32
    return __uint_as_float(v & 0xFFFF0000u);
}
static __device__ __forceinline__ float bf2f(unsigned short v) {
    return __uint_as_float(((unsigned int)v) << 16);
}
static __device__ __forceinline__ unsigned int packbf(float a, float b) {
    return (unsigned int)f2bf(a) | ((unsigned int)f2bf(b) << 16);
}

// B=2, S=2048, C=512, E=512, H=8, HD=64
// reshape(B,H,S,HD) without transpose => per (b,h): contiguous [2048][64] slab
// at flat offset b*1048576 + h*131072 in the [4096][512] projection output.

// =====================================================================
// Kernel 1: fused QKV projection. Y[m,e] = sum_c x[m,c]*W[e,c] + b[e]
// =====================================================================
__global__ __launch_bounds__(256) void qkv_gemm(
    const float* __restrict__ x,
    const float* __restrict__ Wq, const float* __restrict__ bq,
    const float* __restrict__ Wk, const float* __restrict__ bk,
    const float* __restrict__ Wv, const float* __restrict__ bv,
    unsigned short* __restrict__ Qb, unsigned short* __restrict__ Kb,
    unsigned short* __restrict__ Vb)
{
    __shared__ unsigned short As[128 * 40];
    __shared__ unsigned short Bs[128 * 40];

    const int tid  = threadIdx.x;
    const int lane = tid & 63;
    const int wid  = tid >> 6;
    const int g = lane >> 4, c = lane & 15;
    const int wr = wid >> 1, wc = wid & 1;
    const int bm    = blockIdx.x;        // 0..31
    const int widx  = blockIdx.y >> 2;   // 0..2  (Q/K/V)
    const int ntile = blockIdx.y & 3;    // 0..3

    const float* W    = (widx == 0) ? Wq : (widx == 1) ? Wk : Wv;
    const float* bias = (widx == 0) ? bq : (widx == 1) ? bk : bv;
    unsigned short* Y = (widx == 0) ? Qb : (widx == 1) ? Kb : Vb;
    const float* Abase = x + (size_t)bm * 128 * 512;
    const float* Bbase = W + (size_t)ntile * 128 * 512;

    f32x4 acc[4][4];
    #pragma unroll
    for (int m = 0; m < 4; m++)
        #pragma unroll
        for (int n = 0; n < 4; n++) acc[m][n] = (f32x4){0.f, 0.f, 0.f, 0.f};

    for (int kk = 0; kk < 512; kk += 32) {
        #pragma unroll
        for (int i = 0; i < 4; i++) {
            int f  = i * 256 + tid;
            int rr = f >> 3;
            int cc = (f & 7) * 4;
            f32x4 va = *(const f32x4*)(Abase + rr * 512 + kk + cc);
            f32x4 vb = *(const f32x4*)(Bbase + rr * 512 + kk + cc);
            short4v sa, sb;
            #pragma unroll
            for (int q = 0; q < 4; q++) { sa[q] = (short)f2bf(va[q]); sb[q] = (short)f2bf(vb[q]); }
            *(short4v*)(&As[rr * 40 + cc]) = sa;
            *(short4v*)(&Bs[rr * 40 + cc]) = sb;
        }
        __syncthreads();

        short8 af[4], bfr[4];
        #pragma unroll
        for (int m = 0; m < 4; m++) af[m]  = *(const short8*)(&As[(wr * 64 + m * 16 + c) * 40 + g * 8]);
        #pragma unroll
        for (int n = 0; n < 4; n++) bfr[n] = *(const short8*)(&Bs[(wc * 64 + n * 16 + c) * 40 + g * 8]);
        #pragma unroll
        for (int m = 0; m < 4; m++)
            #pragma unroll
            for (int n = 0; n < 4; n++)
                acc[m][n] = MFMA16(af[m], bfr[n], acc[m][n]);
        __syncthreads();
    }

    #pragma unroll
    for (int n = 0; n < 4; n++) {
        int colW = ntile * 128 + wc * 64 + n * 16 + c;
        float bb = bias[colW];
        #pragma unroll
        for (int m = 0; m < 4; m++) {
            #pragma unroll
            for (int r = 0; r < 4; r++) {
                int row = bm * 128 + wr * 64 + m * 16 + g * 4 + r;   // 0..4095
                Y[(size_t)row * 512 + colW] = f2bf(acc[m][n][r] + bb);
            }
        }
    }
}

// =====================================================================
// Kernel 1.5: V transpose.  Vb [4096][512] bf16 -> Vt[bh=16][d=64][s2=2048].
// =====================================================================
__global__ __launch_bounds__(256) void v_transpose(
    const unsigned short* __restrict__ Vb, unsigned short* __restrict__ Vt)
{
    __shared__ unsigned short T[8][520];

    const int tid = threadIdx.x;
    const int t   = blockIdx.x;            // s2 tile
    const int bh  = blockIdx.y;
    const int b = bh >> 3, h = bh & 7;

    #pragma unroll
    for (int i = 0; i < 2; i++) {
        int idx = i * 256 + tid;
        int j   = idx >> 6;
        int cc  = (idx & 63) * 8;
        short8 v = *(const short8*)(Vb + (size_t)(b * 2048 + h * 256 + t * 8 + j) * 512 + cc);
        *(short8*)(&T[j][cc]) = v;
    }
    __syncthreads();

    const int d   = tid >> 2;
    const int sjb = (tid & 3) * 16;
    unsigned short tmp[16];
    #pragma unroll
    for (int i = 0; i < 16; i++) {
        int sj = sjb + i;
        tmp[i] = T[sj >> 3][(sj & 7) * 64 + d];
    }
    unsigned short* dst = Vt + ((size_t)(bh * 64 + d) * 2048) + t * 64 + sjb;
    *(short8*)(dst)     = *(short8*)(&tmp[0]);
    *(short8*)(dst + 8) = *(short8*)(&tmp[8]);
}

// =====================================================================
// Kernel 2: fused attention, single pass, register-resident logits,
// coalesced float4 blend/store phase, XCD-aware block swizzle.
// grid (128, 16) -> flat wg 0..2047; bits [2:0]=xcd, [9:3]=qg, [10]=hi;
// bh = xcd*2 + hi  => each XCD owns exactly 2 heads (K/V stay in its L2).
// =====================================================================
__global__ __launch_bounds__(256) void attn_kernel(
    const unsigned short* __restrict__ Qb, const unsigned short* __restrict__ Kb,
    const unsigned short* __restrict__ Vt,
    const float* __restrict__ dist, const int* __restrict__ mask,
    float* __restrict__ attn_out, unsigned short* __restrict__ ctx_bf)
{
    __shared__ unsigned short AP[4][16][72];   // per-wave P tile (bf16)
    __shared__ float red[4][2][16];            // [wave][max|sum][row]
    __shared__ float Cred[4][16][64];          // PV partials

    const int tid = threadIdx.x;
    const int lane = tid & 63, wid = tid >> 6;
    const int g = lane >> 4, c = lane & 15;

    const int wg  = blockIdx.x + gridDim.x * blockIdx.y;   // 0..2047
    const int qg  = (wg >> 3) & 127;
    const int bh  = (wg & 7) * 2 + ((wg >> 10) & 1);
    const int b = bh >> 3, h = bh & 7;

    const unsigned short* Qh  = Qb + (size_t)b * 1048576 + (size_t)h * 131072;
    const unsigned short* Kh  = Kb + (size_t)b * 1048576 + (size_t)h * 131072;
    const unsigned short* Vth = Vt + (size_t)bh * 131072;       // [64 d][2048 s2]
    const float* distb = dist + (size_t)bh * 4194304;
    float*       outb  = attn_out + (size_t)bh * 4194304;
    const int*   maskb = mask + b * 2048;

    const int qrow    = qg * 16;          // head-local base row
    const int keybase = wid * 512;        // this wave's key range

    short8 qf[2];
    #pragma unroll
    for (int ks = 0; ks < 2; ks++)
        qf[ks] = *(const short8*)(Qh + (size_t)(qrow + c) * 64 + ks * 32 + g * 8);

    // ---------------- phase 1: logits + per-wave max ----------------
    unsigned int pl[8][4][2];             // packed bf16 logits [kb8][n][(r0,r1)|(r2,r3)]
    float lmax[4] = {-3e38f, -3e38f, -3e38f, -3e38f};

    #pragma unroll
    for (int kb8 = 0; kb8 < 8; kb8++) {
        const int kb = keybase + kb8 * 64;
        short8 kf[4][2];
        #pragma unroll
        for (int n = 0; n < 4; n++)
            #pragma unroll
            for (int ks = 0; ks < 2; ks++)
                kf[n][ks] = *(const short8*)(Kh + (size_t)(kb + n * 16 + c) * 64 + ks * 32 + g * 8);
        #pragma unroll
        for (int n = 0; n < 4; n++) {
            f32x4 z = (f32x4){0.f, 0.f, 0.f, 0.f};
            z = MFMA16(qf[0], kf[n][0], z);
            z = MFMA16(qf[1], kf[n][1], z);
            const int mv = maskb[kb + n * 16 + c];
            float l[4];
            #pragma unroll
            for (int r = 0; r < 4; r++) {
                l[r] = mv ? -1250.f : z[r] * 0.125f;
                lmax[r] = fmaxf(lmax[r], l[r]);
            }
            pl[kb8][n][0] = packbf(l[0], l[1]);
            pl[kb8][n][1] = packbf(l[2], l[3]);
        }
    }
    #pragma unroll
    for (int r = 0; r < 4; r++) {
        #pragma unroll
        for (int off = 1; off < 16; off <<= 1)
            lmax[r] = fmaxf(lmax[r], __shfl_xor(lmax[r], off));
    }
    if (c == 0) {
        #pragma unroll
        for (int r = 0; r < 4; r++) red[wid][0][g * 4 + r] = lmax[r];
    }
    __syncthreads();
    float m[4];
    #pragma unroll
    for (int r = 0; r < 4; r++) {
        int row = g * 4 + r;
        m[r] = fmaxf(fmaxf(red[0][0][row], red[1][0][row]),
                     fmaxf(red[2][0][row], red[3][0][row]));
    }

    // ---------------- phase 2: exp + denom ----------------
    float dsum[4] = {0.f, 0.f, 0.f, 0.f};
    #pragma unroll
    for (int kb8 = 0; kb8 < 8; kb8++) {
        #pragma unroll
        for (int n = 0; n < 4; n++) {
            #pragma unroll
            for (int pi = 0; pi < 2; pi++) {
                unsigned int v = pl[kb8][n][pi];
                float e0 = __expf(bflo(v) - m[pi * 2]);
                float e1 = __expf(bfhi(v) - m[pi * 2 + 1]);
                dsum[pi * 2]     += e0;
                dsum[pi * 2 + 1] += e1;
                pl[kb8][n][pi] = packbf(e0, e1);
            }
        }
    }
    #pragma unroll
    for (int r = 0; r < 4; r++) {
        #pragma unroll
        for (int off = 1; off < 16; off <<= 1)
            dsum[r] += __shfl_xor(dsum[r], off);
    }
    if (c == 0) {
        #pragma unroll
        for (int r = 0; r < 4; r++) red[wid][1][g * 4 + r] = dsum[r];
    }
    __syncthreads();
    float invd[4];
    #pragma unroll
    for (int r = 0; r < 4; r++) {
        int row = g * 4 + r;
        invd[r] = 1.f / (red[0][1][row] + red[1][1][row] + red[2][1][row] + red[3][1][row]);
    }

    // ---------------- phase 3: p->LDS, coalesced blend+store, PV ----------------
    f32x4 cacc[4];
    #pragma unroll
    for (int nd = 0; nd < 4; nd++) cacc[nd] = (f32x4){0.f, 0.f, 0.f, 0.f};

    #pragma unroll
    for (int kb8 = 0; kb8 < 8; kb8++) {
        const int kb = keybase + kb8 * 64;

        // (a) issue dist loads first: lane covers (row = rg*4+g, cols c*4..c*4+3)
        //     -> per instruction 4 segments x 256B (full lines), no dependencies
        f32x4 dv[4];
        #pragma unroll
        for (int rg = 0; rg < 4; rg++)
            dv[rg] = *(const f32x4*)(distb + (size_t)(qrow + rg * 4 + g) * 2048 + kb + c * 4);

        // (b) normalize p and write to AP in MFMA C-layout
        #pragma unroll
        for (int n = 0; n < 4; n++) {
            #pragma unroll
            for (int pi = 0; pi < 2; pi++) {
                unsigned int v = pl[kb8][n][pi];
                AP[wid][g * 4 + pi * 2    ][n * 16 + c] = f2bf(bflo(v) * invd[pi * 2]);
                AP[wid][g * 4 + pi * 2 + 1][n * 16 + c] = f2bf(bfhi(v) * invd[pi * 2 + 1]);
            }
        }

        // (c) blend in row-streaming layout: float4 stores (4 x 256B segments)
        #pragma unroll
        for (int rg = 0; rg < 4; rg++) {
            const int row = rg * 4 + g;
            short4v pv = *(const short4v*)(&AP[wid][row][c * 4]);
            f32x4 apv;
            #pragma unroll
            for (int q = 0; q < 4; q++)
                apv[q] = 0.5f * (bf2f((unsigned short)pv[q]) + dv[rg][q]);
            *(f32x4*)(outb + (size_t)(qrow + row) * 2048 + kb + c * 4) = apv;
            short4v apb;
            #pragma unroll
            for (int q = 0; q < 4; q++) apb[q] = (short)f2bf(apv[q]);
            *(short4v*)(&AP[wid][row][c * 4]) = apb;
        }

        // (d) PV: A-frags of blended probs from LDS, V from L2
        short8 apf[2];
        #pragma unroll
        for (int ks = 0; ks < 2; ks++)
            apf[ks] = *(const short8*)(&AP[wid][c][ks * 32 + g * 8]);
        #pragma unroll
        for (int nd = 0; nd < 4; nd++) {
            #pragma unroll
            for (int ks = 0; ks < 2; ks++) {
                short8 vf = *(const short8*)(Vth + (size_t)(nd * 16 + c) * 2048 + kb + ks * 32 + g * 8);
                cacc[nd] = MFMA16(apf[ks], vf, cacc[nd]);
            }
        }
    }

    // ---------------- phase 4: cross-wave PV reduce + ctx store ----------------
    #pragma unroll
    for (int nd = 0; nd < 4; nd++)
        #pragma unroll
        for (int r = 0; r < 4; r++)
            Cred[wid][g * 4 + r][nd * 16 + c] = cacc[nd][r];
    __syncthreads();

    for (int e = tid; e < 1024; e += 256) {
        int row = e >> 6, d = e & 63;
        float s = Cred[0][row][d] + Cred[1][row][d] + Cred[2][row][d] + Cred[3][row][d];
        int i = qrow + row;
        ctx_bf[(size_t)(b * 2048 + i) * 512 + h * 64 + d] = f2bf(s);
    }
}

// =====================================================================
// Kernel 3: out = ctx @ Wo^T + bo.  A bf16 [4096][512], B fp32 [512][512] (NT).
// =====================================================================
__global__ __launch_bounds__(256) void out_gemm(
    const unsigned short* __restrict__ A,
    const float* __restrict__ Wo, const float* __restrict__ bo,
    float* __restrict__ out)
{
    __shared__ unsigned short As[128 * 40];
    __shared__ unsigned short Bs[128 * 40];

    const int tid  = threadIdx.x;
    const int lane = tid & 63;
    const int wid  = tid >> 6;
    const int g = lane >> 4, c = lane & 15;
    const int wr = wid >> 1, wc = wid & 1;
    const int bm    = blockIdx.x;
    const int ntile = blockIdx.y;

    const unsigned short* Abase = A + (size_t)bm * 128 * 512;
    const float* Bbase = Wo + (size_t)ntile * 128 * 512;

    f32x4 acc[4][4];
    #pragma unroll
    for (int m = 0; m < 4; m++)
        #pragma unroll
        for (int n = 0; n < 4; n++) acc[m][n] = (f32x4){0.f, 0.f, 0.f, 0.f};

    for (int kk = 0; kk < 512; kk += 32) {
        #pragma unroll
        for (int i = 0; i < 2; i++) {
            int f8 = i * 256 + tid;
            int rr = f8 >> 2;
            int cc = (f8 & 3) * 8;
            short8 va = *(const short8*)(Abase + (size_t)rr * 512 + kk + cc);
            *(short8*)(&As[rr * 40 + cc]) = va;
        }
        #pragma unroll
        for (int i = 0; i < 4; i++) {
            int f  = i * 256 + tid;
            int rr = f >> 3;
            int cc = (f & 7) * 4;
            f32x4 vb = *(const f32x4*)(Bbase + (size_t)rr * 512 + kk + cc);
            short4v sb;
            #pragma unroll
            for (int q = 0; q < 4; q++) sb[q] = (short)f2bf(vb[q]);
            *(short4v*)(&Bs[rr * 40 + cc]) = sb;
        }
        __syncthreads();

        short8 af[4], bfr[4];
        #pragma unroll
        for (int m = 0; m < 4; m++) af[m]  = *(const short8*)(&As[(wr * 64 + m * 16 + c) * 40 + g * 8]);
        #pragma unroll
        for (int n = 0; n < 4; n++) bfr[n] = *(const short8*)(&Bs[(wc * 64 + n * 16 + c) * 40 + g * 8]);
        #pragma unroll
        for (int m = 0; m < 4; m++)
            #pragma unroll
            for (int n = 0; n < 4; n++)
                acc[m][n] = MFMA16(af[m], bfr[n], acc[m][n]);
        __syncthreads();
    }

    #pragma unroll
    for (int n = 0; n < 4; n++) {
        int col = ntile * 128 + wc * 64 + n * 16 + c;
        float bb = bo[col];
        #pragma unroll
        for (int m = 0; m < 4; m++) {
            #pragma unroll
            for (int r = 0; r < 4; r++) {
                int row = bm * 128 + wr * 64 + m * 16 + g * 4 + r;
                out[(size_t)row * 512 + col] = acc[m][n][r] + bb;
            }
        }
    }
}

// =====================================================================
extern "C" void kernel_launch(void* const* d_in, const int* in_sizes, int n_in,
                              void* d_out, int out_size, void* d_ws, size_t ws_size,
                              hipStream_t stream)
{
    const float* x    = (const float*)d_in[0];
    const float* dist = (const float*)d_in[1];
    const int*   mask = (const int*)d_in[2];
    const float* Wq   = (const float*)d_in[3];
    const float* bq   = (const float*)d_in[4];
    const float* Wk   = (const float*)d_in[5];
    const float* bk   = (const float*)d_in[6];
    const float* Wv   = (const float*)d_in[7];
    const float* bv   = (const float*)d_in[8];
    const float* Wo   = (const float*)d_in[9];
    const float* bo   = (const float*)d_in[10];

    float* out      = (float*)d_out;            // (2,2048,512)   = 2,097,152
    float* attn_out = out + 2097152;            // (2,8,2048,2048)= 67,108,864

    char* ws = (char*)d_ws;
    unsigned short* Qb  = (unsigned short*)(ws);                 // 4 MB
    unsigned short* Kb  = (unsigned short*)(ws + (4u << 20));    // 4 MB
    unsigned short* Vb  = (unsigned short*)(ws + (8u << 20));    // 4 MB (linear V)
    unsigned short* Vt  = (unsigned short*)(ws + (12u << 20));   // 4 MB [16][64][2048]
    unsigned short* ctx = (unsigned short*)(ws + (8u << 20));    // reuses Vb (consumed)

    qkv_gemm   <<<dim3(32, 12), 256, 0, stream>>>(x, Wq, bq, Wk, bk, Wv, bv, Qb, Kb, Vb);
    v_transpose<<<dim3(32, 16), 256, 0, stream>>>(Vb, Vt);
    attn_kernel<<<dim3(128, 16), 256, 0, stream>>>(Qb, Kb, Vt, dist, mask, attn_out, ctx);
    out_gemm   <<<dim3(32, 4),  256, 0, stream>>>(ctx, Wo, bo, out);
}